// Round 5
// baseline (241.946 us; speedup 1.0000x reference)
//
#include <hip/hip_runtime.h>

// ---------------------------------------------------------------------------
// GenView, round 5.
//
// Algebra (verified R1-R4): per-row softmax cancels emb[row]·w1 and biases.
//   q[n] = feat[n] . (W @ w2)            GEMV, 51.2 MB feat read
//   t[n] = exp( sum_{e:row=n} v[e]*q[col[e]] )
//   S[n] = sum_{e:row=n} t[col[e]]
//   out[e] = vori[e] + t[col[e]] / S[row[e]]
//
// Segment sums via atomic-free bucket sort (row>>7 -> 391 buckets x 128 rows,
// rec = (col<<7|row&127, v)). R4 lesson: bucket kernels ran at ~6 waves/CU ->
// latency-bound (~135 us total). R5: 1024-thread blocks / 1024-block grids
// everywhere in the sort path; exp fused into the B-pass epilogue.
// Fixed harness overhead (ws re-poison fill + input restore) ~ 94 us.
// ---------------------------------------------------------------------------

typedef unsigned int u32;

#define RPB     128          // rows per bucket
#define NB_MAX  512          // max buckets (N <= 65536)
#define SBLK    1024         // hist/scatter grid size == scan2 block size

// ---------------- u2[f] = sum_h W[f,h] * mw[H+h] ----------------
__global__ void k_prep_u(const float* __restrict__ W, const float* __restrict__ mw,
                         float* __restrict__ u2, int F, int H) {
  int f = blockIdx.x * blockDim.x + threadIdx.x;
  if (f >= F) return;
  const float* wr = W + (size_t)f * H;
  float s = 0.f;
  for (int h = 0; h < H; ++h) s = fmaf(wr[h], mw[H + h], s);
  u2[f] = s;
}

// ---------------- q[r] = feat[r] . u2 ; 16 lanes/row, 4 rows/wave ----------
template <int F>
__global__ void k_gemv(const float* __restrict__ feat, const float* __restrict__ u2,
                       float* __restrict__ q, int N) {
  const int lane = threadIdx.x & 63;
  const int sub  = lane & 15;
  const int grp  = lane >> 4;
  const int wid  = (blockIdx.x * blockDim.x + threadIdx.x) >> 6;
  const int r    = wid * 4 + grp;
  float4 uf[F / 64];
#pragma unroll
  for (int i = 0; i < F / 64; ++i)
    uf[i] = *(const float4*)(u2 + i * 64 + sub * 4);
  float a = 0.f;
  if (r < N) {
    const float* fr = feat + (size_t)r * F;
#pragma unroll
    for (int i = 0; i < F / 64; ++i) {
      float4 v = *(const float4*)(fr + i * 64 + sub * 4);
      a = fmaf(v.x, uf[i].x, fmaf(v.y, uf[i].y,
          fmaf(v.z, uf[i].z, fmaf(v.w, uf[i].w, a))));
    }
  }
  a += __shfl_xor(a, 8);
  a += __shfl_xor(a, 4);
  a += __shfl_xor(a, 2);
  a += __shfl_xor(a, 1);
  if (sub == 0 && r < N) q[r] = a;
}

// ---------------- per-block bucket histogram -> Ht[b][blk] ----------------
__global__ void k_hist(const int* __restrict__ row, int E, int chunk,
                       u32* __restrict__ Ht, int nb) {
  __shared__ u32 h[NB_MAX];
  for (int s = threadIdx.x; s < nb; s += blockDim.x) h[s] = 0;
  __syncthreads();
  const int lo = blockIdx.x * chunk;
  const int hi = min(E, lo + chunk);
  for (int e = lo + threadIdx.x; e < hi; e += blockDim.x)
    atomicAdd(&h[row[e] >> 7], 1u);
  __syncthreads();
  for (int s = threadIdx.x; s < nb; s += blockDim.x)
    Ht[(size_t)s * SBLK + blockIdx.x] = h[s];
}

// ---- per-bucket exclusive scan over blocks; Ht -> rel (in place), P[b] ----
__global__ void k_scan2(u32* __restrict__ Ht, u32* __restrict__ P) {
  __shared__ u32 a[2][SBLK];
  const int b = blockIdx.x, t = threadIdx.x;
  u32 c = Ht[(size_t)b * SBLK + t];
  a[0][t] = c;
  __syncthreads();
  int src = 0;
  for (int off = 1; off < SBLK; off <<= 1) {
    a[1 ^ src][t] = a[src][t] + ((t >= off) ? a[src][t - off] : 0);
    __syncthreads();
    src ^= 1;
  }
  u32 incl = a[src][t];
  Ht[(size_t)b * SBLK + t] = incl - c;          // rel
  if (t == SBLK - 1) P[b] = incl;               // bucket total
}

// ---------------- exclusive scan over buckets: P -> base[0..nb] ----------------
__global__ void k_scan1(const u32* __restrict__ P, u32* __restrict__ base, int nb) {
  __shared__ u32 a[2][NB_MAX];
  const int t = threadIdx.x;
  u32 c = (t < nb) ? P[t] : 0;
  a[0][t] = c;
  __syncthreads();
  int src = 0;
  for (int off = 1; off < NB_MAX; off <<= 1) {
    a[1 ^ src][t] = a[src][t] + ((t >= off) ? a[src][t - off] : 0);
    __syncthreads();
    src ^= 1;
  }
  u32 incl = a[src][t];
  if (t < nb) base[t] = incl - c;
  if (t == nb - 1) base[nb] = incl;
}

// ---------------- scatter edges into bucket-ordered records ----------------
__global__ void k_scatter(const int* __restrict__ row, const int* __restrict__ col,
                          const float* __restrict__ v, int E, int chunk,
                          const u32* __restrict__ rel, const u32* __restrict__ base,
                          uint2* __restrict__ rec, int nb) {
  __shared__ u32 start[NB_MAX];
  __shared__ u32 rk[NB_MAX];
  const int blk = blockIdx.x;
  for (int s = threadIdx.x; s < nb; s += blockDim.x) {
    start[s] = base[s] + rel[(size_t)s * SBLK + blk];
    rk[s] = 0;
  }
  __syncthreads();
  const int lo = blk * chunk;
  const int hi = min(E, lo + chunk);
  for (int e = lo + threadIdx.x; e < hi; e += blockDim.x) {
    int r = row[e];
    int b = r >> 7;
    u32 rank = atomicAdd(&rk[b], 1u);
    rec[start[b] + rank] = make_uint2(((u32)col[e] << 7) | (u32)(r & 127),
                                      __float_as_uint(v[e]));
  }
}

// ---------------- per-bucket segment sum (one block per bucket) ----------------
// mode 0: out[row] = exp( sum v * g[col] )   (g = q, produces t)
// mode 1: out[row] = sum g[col]              (g = t, produces S)
__global__ void k_bucket_sum(const uint2* __restrict__ rec, const u32* __restrict__ base,
                             const float* __restrict__ g, float* __restrict__ out,
                             int mode) {
  __shared__ float acc[RPB];
  const int b = blockIdx.x;
  const int tid = threadIdx.x;
  if (tid < RPB) acc[tid] = 0.f;
  __syncthreads();
  const u32 lo = base[b], hi = base[b + 1];
  for (u32 i = lo + tid; i < hi; i += blockDim.x) {
    uint2 rr = rec[i];
    float gv = g[rr.x >> 7];
    atomicAdd(&acc[rr.x & 127], mode ? gv : gv * __uint_as_float(rr.y));
  }
  __syncthreads();
  if (tid < RPB)
    out[b * RPB + tid] = mode ? acc[tid] : __expf(acc[tid]);
}

// ---------------- out[e] = vori[e] + t[col]/S[row] ----------------
__global__ void k_out(const int* __restrict__ row, const int* __restrict__ col,
                      const float* __restrict__ vori, const float* __restrict__ t,
                      const float* __restrict__ S, float* __restrict__ out, int E) {
  int e = blockIdx.x * blockDim.x + threadIdx.x;
  if (e >= E) return;
  out[e] = vori[e] + t[col[e]] / S[row[e]];
}

// ---------------- fallback (ws too small): global-atomic path ----------------
__global__ void k_scatter_B_at(const int* __restrict__ row, const int* __restrict__ col,
                               const float* __restrict__ v, const float* __restrict__ q,
                               float* __restrict__ B, int E) {
  int e = blockIdx.x * blockDim.x + threadIdx.x;
  if (e >= E) return;
  atomicAdd(&B[row[e]], v[e] * q[col[e]]);
}
__global__ void k_node_t(const float* __restrict__ B, float* __restrict__ t, int N) {
  int n = blockIdx.x * blockDim.x + threadIdx.x;
  if (n < N) t[n] = __expf(B[n]);
}
__global__ void k_scatter_S_at(const int* __restrict__ row, const int* __restrict__ col,
                               const float* __restrict__ t, float* __restrict__ S, int E) {
  int e = blockIdx.x * blockDim.x + threadIdx.x;
  if (e >= E) return;
  atomicAdd(&S[row[e]], t[col[e]]);
}

extern "C" void kernel_launch(void* const* d_in, const int* in_sizes, int n_in,
                              void* d_out, int out_size, void* d_ws, size_t ws_size,
                              hipStream_t stream) {
  const float* vori = (const float*)d_in[0];
  const float* feat = (const float*)d_in[1];
  const int*   vind = (const int*)d_in[2];
  const float* W    = (const float*)d_in[4];
  const float* mw   = (const float*)d_in[6];

  const int E = in_sizes[0];
  const int H = in_sizes[6] / 2;        // 128
  const int F = in_sizes[4] / H;        // 512
  const int N = in_sizes[1] / F;        // 50000

  const int* row = vind;
  const int* col = vind + E;

  const int nb   = (N + RPB - 1) / RPB; // 391
  const int npad = nb * RPB;

  // ---- workspace: u2(F) q(N) t(npad) S(npad) | Ht(nb*SBLK) P(nb) base(nb+1) | rec(E)
  float* ws  = (float*)d_ws;
  float* u2  = ws;
  float* q   = u2 + F;
  float* t   = q + N;
  float* S   = t + npad;
  u32* Ht    = (u32*)(S + npad);
  u32* P     = Ht + (size_t)nb * SBLK;
  u32* base  = P + nb;
  size_t hdr = (size_t)((char*)(base + nb + 1) - (char*)d_ws);
  hdr = (hdr + 7) & ~(size_t)7;
  uint2* rec = (uint2*)((char*)d_ws + hdr);
  size_t need = hdr + (size_t)E * sizeof(uint2);

  const int eb  = (E + 255) / 256;
  const int nbk = (N + 255) / 256;

  k_prep_u<<<(F + 255) / 256, 256, 0, stream>>>(W, mw, u2, F, H);
  k_gemv<512><<<(N + 15) / 16, 256, 0, stream>>>(feat, u2, q, N);   // 3125 blocks

  if (ws_size >= need && F == 512 && nb <= NB_MAX) {
    const int chunk = (E + SBLK - 1) / SBLK;                        // 782
    k_hist<<<SBLK, 256, 0, stream>>>(row, E, chunk, Ht, nb);
    k_scan2<<<nb, SBLK, 0, stream>>>(Ht, P);                        // 1024-thr blocks
    k_scan1<<<1, NB_MAX, 0, stream>>>(P, base, nb);
    k_scatter<<<SBLK, 256, 0, stream>>>(row, col, vori, E, chunk, Ht, base, rec, nb);
    k_bucket_sum<<<nb, 1024, 0, stream>>>(rec, base, q, t, 0);      // t = exp(B)
    k_bucket_sum<<<nb, 1024, 0, stream>>>(rec, base, t, S, 1);      // S
    k_out<<<eb, 256, 0, stream>>>(row, col, vori, t, S, (float*)d_out, E);
  } else {
    // fallback: global-atomic segment sums (B in S buffer, then S overwrites)
    hipMemsetAsync((void*)S, 0, sizeof(float) * (size_t)npad, stream);
    k_scatter_B_at<<<eb, 256, 0, stream>>>(row, col, vori, q, S, E);
    k_node_t<<<nbk, 256, 0, stream>>>(S, t, N);
    hipMemsetAsync((void*)S, 0, sizeof(float) * (size_t)npad, stream);
    k_scatter_S_at<<<eb, 256, 0, stream>>>(row, col, t, S, E);
    k_out<<<eb, 256, 0, stream>>>(row, col, vori, t, S, (float*)d_out, E);
  }
}